// Round 4
// baseline (252.866 us; speedup 1.0000x reference)
//
#include <hip/hip_runtime.h>
#include <hip/hip_bf16.h>

#define BB 4
#define TT 4096
#define CC 1024
#define HH 64

typedef _Float16 f16;
typedef __attribute__((ext_vector_type(8))) _Float16 f16x8;
typedef __attribute__((ext_vector_type(4))) _Float16 f16x4;
typedef __attribute__((ext_vector_type(4))) float f32x4;

#define MFMA32(a,b,c) __builtin_amdgcn_mfma_f32_16x16x32_f16((a),(b),(c),0,0,0)
#define MFMA16(a,b,c) __builtin_amdgcn_mfma_f32_16x16x16f16((a),(b),(c),0,0,0)

// frag-major sizes (f16 units)
#define WF_ELEMS (3 * 32 * 4 * 64 * 8)        // 196,608
#define CHUNK_F16 1024                        // per 16-row chunk: 2 halves x 64 lanes x 8
#define PB_F16 (256 * CHUNK_F16)              // per batch: 256 chunks

// Async global->LDS, 16B per lane. Side-effecting: compiler cannot sink it.
// LDS dest must be wave-uniform; lane i's 16B lands at dest + i*16.
static __device__ __forceinline__ void gl_lds16(const void* g, void* l) {
  __builtin_amdgcn_global_load_lds(
      (const __attribute__((address_space(1))) unsigned int*)g,
      (__attribute__((address_space(3))) unsigned int*)l, 16, 0, 0);
}

static __device__ __forceinline__ f16x8 pack2(f32x4 a, f32x4 b) {
  f16x8 r;
  r[0]=(f16)a[0]; r[1]=(f16)a[1]; r[2]=(f16)a[2]; r[3]=(f16)a[3];
  r[4]=(f16)b[0]; r[5]=(f16)b[1]; r[6]=(f16)b[2]; r[7]=(f16)b[3];
  return r;
}

// ---------------------------------------------------------------------------
// Repack W -> frag-major f16. Block bx = (p*32+kc)*4+nt, 64 threads.
// Softmax double-scale log2(e)/64 folded into Wq.
// ---------------------------------------------------------------------------
__global__ __launch_bounds__(64) void wrepack_kernel(
    const float* __restrict__ Wqg, const float* __restrict__ Wkg,
    const float* __restrict__ Wvg, f16* __restrict__ Wf)
{
  const int bx = blockIdx.x;
  const int nt = bx & 3;
  const int kc = (bx >> 2) & 31;
  const int p  = bx >> 7;
  const float* W = (p == 0) ? Wqg : (p == 1) ? Wkg : Wvg;
  const float sc = (p == 0) ? (1.4426950408889634f / 64.0f) : 1.0f;

  const int lane = threadIdx.x;
  const int l16 = lane & 15, quad = lane >> 4;
  const float* src = W + (size_t)(nt * 16 + l16) * CC + kc * 32 + quad * 8;
  f32x4 a = *(const f32x4*)src;
  f32x4 b = *(const f32x4*)(src + 4);
  f16x8 r;
  #pragma unroll
  for (int j = 0; j < 4; ++j) { r[j] = (f16)(a[j] * sc); r[j + 4] = (f16)(b[j] * sc); }
  *(f16x8*)(Wf + (size_t)bx * 512 + lane * 8) = r;
}

// ---------------------------------------------------------------------------
// Projection: X[16384,1024] fp32 x W^T -> frag-major f16.
// Register-pipelined streaming version. Evidence across R0-R3: gl_lds-staged
// variants (scattered OR contiguous) and compiler-scheduled plain loads all
// pin at ~4 B/cyc/CU (1.2-1.4 TB/s); m13's plain-load copy achieves 25.6
// B/cyc/CU. Theory: the LDS-DMA path pipelines L2 MISSES poorly, and plain
// loads are fast only with real register-level prefetch distance (R1's
// VGPR=56 showed the compiler kept ~1 load in flight).
// Structure: wave-independent (zero barriers). A-frags loaded directly from
// global (lane(l16,quad) owns row l16, bytes kc*128+quad*32..+31 -- exactly
// the MFMA A layout) into a depth-3 rotating register pipeline; W frags
// (L2-hot, 128KB/tensor shared by all blocks) depth-2. Consume slot s, then
// refill it for step s+3 -- all slot indices compile-time under full unroll.
// ~95-110 live VGPRs of pipeline state; launch_bounds(256,3) gives 170-VGPR
// headroom so the scheduler has no pressure incentive to sink loads.
// Per wave in flight: 3x2KB A + 2x4KB W = 14KB; x12 waves/CU >> Little's-law
// requirement (~10KB/CU at ~900cy miss latency).
// ---------------------------------------------------------------------------
__global__ __launch_bounds__(256, 3) void proj_kernel(
    const float* __restrict__ qg, const float* __restrict__ kg, const float* __restrict__ vg,
    const f16* __restrict__ Wf,
    f16* __restrict__ Qf, f16* __restrict__ Kf, f16* __restrict__ Vf)
{
  __shared__ f16 Lsw[4][16][66];   // per-wave transpose scratch, 8.25 KB

  const float* X; f16* O; const int p = blockIdx.y;
  if (p == 0)      { X = qg; O = Qf; }
  else if (p == 1) { X = kg; O = Kf; }
  else             { X = vg; O = Vf; }

  const int tid  = threadIdx.x;
  const int w    = tid >> 6;
  const int lane = tid & 63;
  const int quad = lane >> 4;
  const int l16  = lane & 15;
  const int r0   = blockIdx.x * 64 + w * 16;   // wave's 16-row tile

  // lane's A source: row r0+l16, k-offset quad*8 within each 32-float K-chunk
  const float* xrow = X + (size_t)(r0 + l16) * CC + quad * 8;
  // lane's B source: frag-major W, 16B per lane, contiguous 1KB per wave-read
  const f16* wbase = Wf + (size_t)p * 128 * 512 + lane * 8;

  f32x4 acc[4];
  #pragma unroll
  for (int nt = 0; nt < 4; ++nt) acc[nt] = (f32x4){0.f, 0.f, 0.f, 0.f};

  // software pipeline: A depth 3, W depth 2 (rotating, static indices)
  f32x4 Ap[3][2];
  f16x8 Wp[2][4];
  #pragma unroll
  for (int i = 0; i < 3; ++i) {
    Ap[i][0] = *(const f32x4*)(xrow + i * 32);
    Ap[i][1] = *(const f32x4*)(xrow + i * 32 + 4);
  }
  #pragma unroll
  for (int i = 0; i < 2; ++i)
    #pragma unroll
    for (int nt = 0; nt < 4; ++nt)
      Wp[i][nt] = *(const f16x8*)(wbase + ((size_t)i * 4 + nt) * 512);

  #pragma unroll
  for (int s = 0; s < 32; ++s) {
    // consume step s
    f16x8 af = pack2(Ap[s % 3][0], Ap[s % 3][1]);
    #pragma unroll
    for (int nt = 0; nt < 4; ++nt)
      acc[nt] = MFMA32(af, Wp[s & 1][nt], acc[nt]);
    // refill freed slots (clamped tail refills hit L1, never consumed)
    const int ka = (s + 3 < 32) ? s + 3 : 31;
    const int kw = (s + 2 < 32) ? s + 2 : 31;
    Ap[s % 3][0] = *(const f32x4*)(xrow + ka * 32);
    Ap[s % 3][1] = *(const f32x4*)(xrow + ka * 32 + 4);
    #pragma unroll
    for (int nt = 0; nt < 4; ++nt)
      Wp[s & 1][nt] = *(const f16x8*)(wbase + ((size_t)kw * 4 + nt) * 512);
  }

  // epilogue: C-layout acc -> frag-major via wave-private LDS scratch.
  // Same-wave ds_write -> ds_read: compiler orders via lgkmcnt; no barrier.
  f16 (*Ls)[66] = Lsw[w];
  #pragma unroll
  for (int nt = 0; nt < 4; ++nt)
    #pragma unroll
    for (int r = 0; r < 4; ++r)
      Ls[quad * 4 + r][nt * 16 + l16] = (f16)acc[nt][r];
  const size_t chunk = (size_t)blockIdx.x * 4 + w;
  if (p < 2) {
    // Q/K frag: [chunk][half][lane][8] = tile[row=l16][hd=32h+8q+j]
    #pragma unroll
    for (int h = 0; h < 2; ++h) {
      f16x8 t = *(const f16x8*)&Ls[l16][h * 32 + quad * 8];
      *(f16x8*)(O + (chunk * 2 + h) * 512 + lane * 8) = t;
    }
  } else {
    // V frag: [chunk][np][lane][8] = tile[key=4q+(j&3)][hd=(2np+(j>>2))*16+l16]
    #pragma unroll
    for (int np = 0; np < 2; ++np) {
      f16x8 t;
      #pragma unroll
      for (int j = 0; j < 8; ++j)
        t[j] = Ls[quad * 4 + (j & 3)][(2 * np + (j >> 2)) * 16 + l16];
      *(f16x8*)(O + (chunk * 2 + np) * 512 + lane * 8) = t;
    }
  }
}

// ---------------------------------------------------------------------------
// Flash attention, mask s <= t+1. Block-wide double-buffered async staging of
// K and V steps (each step = contiguous 8 KB in frag-major layout). Frag reads
// are lane-linear ds_read_b128 (conflict-free). Uniform trip counts.
// S^T via MFMA(A=K,B=Q); P C-layout == MFMA16 A-layout. Scale folded into Wq.
// ---------------------------------------------------------------------------
__device__ __forceinline__ void attn_tile(
    int b, int j, int a, int e, int wave, int quad, int l16, int lane, int sp,
    const f16* __restrict__ Qf, const f16* __restrict__ Kf, const f16* __restrict__ Vf,
    f16 (*Ks)[8][64][8], f16 (*Vs)[8][64][8],
    float* __restrict__ Opart, float* __restrict__ lpart)
{
  const int m0 = j * 64 + wave * 16;

  const f16* Kfb = Kf + (size_t)b * PB_F16;
  const f16* Vfb = Vf + (size_t)b * PB_F16;
  const f16* Qfb = Qf + (size_t)b * PB_F16;

  f16x8 qa0 = *(const f16x8*)(Qfb + ((size_t)(m0 >> 4) * 2 + 0) * 512 + lane * 8);
  f16x8 qa1 = *(const f16x8*)(Qfb + ((size_t)(m0 >> 4) * 2 + 1) * 512 + lane * 8);

  f32x4 o[4];
  float lsum = 0.f;
  #pragma unroll
  for (int nt = 0; nt < 4; ++nt) o[nt] = (f32x4){0.f, 0.f, 0.f, 0.f};

  // protect staging buffers from the previous tile's laggard readers
  __syncthreads();

  if (a < e) {
    #pragma unroll
    for (int jj = 0; jj < 2; ++jj) {
      const int idx = 2 * wave + jj;
      gl_lds16(Kfb + (size_t)a * 4096 + idx * 512 + lane * 8, &Ks[0][idx][0][0]);
      gl_lds16(Vfb + (size_t)a * 4096 + idx * 512 + lane * 8, &Vs[0][idx][0][0]);
    }
  }

  for (int st = a; st < e; ++st) {
    const int buf = (st - a) & 1;
    __syncthreads();   // drains staging of buf
    if (st + 1 < e) {
      #pragma unroll
      for (int jj = 0; jj < 2; ++jj) {
        const int idx = 2 * wave + jj;
        gl_lds16(Kfb + (size_t)(st + 1) * 4096 + idx * 512 + lane * 8, &Ks[buf ^ 1][idx][0][0]);
        gl_lds16(Vfb + (size_t)(st + 1) * 4096 + idx * 512 + lane * 8, &Vs[buf ^ 1][idx][0][0]);
      }
    }
    const int s0 = st * 64;

    // S^T = K Q^T (scale pre-folded into Q)
    f32x4 sc[4];
    #pragma unroll
    for (int ct = 0; ct < 4; ++ct) {
      f16x8 k0 = *(const f16x8*)&Ks[buf][ct * 2][lane][0];
      f16x8 k1 = *(const f16x8*)&Ks[buf][ct * 2 + 1][lane][0];
      f32x4 z = (f32x4){0.f, 0.f, 0.f, 0.f};
      z = MFMA32(k0, qa0, z);
      sc[ct] = MFMA32(k1, qa1, z);
    }

    // mask + exp2; lane: query=m0+l16, key=s0+ct*16+quad*4+r
    const bool domask = (s0 + 63) > (m0 + 1);
    f16x4 pa[4];
    #pragma unroll
    for (int ct = 0; ct < 4; ++ct) {
      #pragma unroll
      for (int r = 0; r < 4; ++r) {
        float x = sc[ct][r];
        if (domask) {
          const int key = s0 + ct * 16 + quad * 4 + r;
          if (key > m0 + l16 + 1) x = -__builtin_inff();
        }
        const float pv = __builtin_amdgcn_exp2f(x);
        lsum += pv;
        pa[ct][r] = (f16)pv;
      }
    }

    // PV: A=P (MFMA16 A-layout), B=V frag halves
    #pragma unroll
    for (int ct = 0; ct < 4; ++ct) {
      #pragma unroll
      for (int np = 0; np < 2; ++np) {
        f16x8 vv = *(const f16x8*)&Vs[buf][ct * 2 + np][lane][0];
        f16x4 blo = __builtin_shufflevector(vv, vv, 0, 1, 2, 3);
        f16x4 bhi = __builtin_shufflevector(vv, vv, 4, 5, 6, 7);
        o[2 * np]     = MFMA16(pa[ct], blo, o[2 * np]);
        o[2 * np + 1] = MFMA16(pa[ct], bhi, o[2 * np + 1]);
      }
    }
  }

  lsum += __shfl_xor(lsum, 16, 64);
  lsum += __shfl_xor(lsum, 32, 64);
  const size_t rbase = (size_t)(sp * BB + b) * TT;
  if (quad == 0) lpart[rbase + m0 + l16] = lsum;
  #pragma unroll
  for (int nt = 0; nt < 4; ++nt)
    #pragma unroll
    for (int r = 0; r < 4; ++r)
      Opart[(rbase + m0 + quad * 4 + r) * HH + nt * 16 + l16] = o[nt][r];
}

__global__ __launch_bounds__(256) void attn_kernel(
    const f16* __restrict__ Qf, const f16* __restrict__ Kf, const f16* __restrict__ Vf,
    float* __restrict__ Opart, float* __restrict__ lpart, int S)
{
  __shared__ f16 Ks[2][8][64][8];   // 16 KB
  __shared__ f16 Vs[2][8][64][8];   // 16 KB

  const int pr = blockIdx.x;
  const int sp = blockIdx.y;
  const int b  = blockIdx.z;
  const int tid  = threadIdx.x;
  const int wave = tid >> 6;
  const int lane = tid & 63;
  const int quad = lane >> 4;
  const int l16  = lane & 15;

  const int j1 = pr, j2 = 63 - pr;
  const int n1 = min(j1 + 2, 64), n2 = min(j2 + 2, 64);
  const int tot = n1 + n2;
  const int lo = tot * sp / S, hi = tot * (sp + 1) / S;
  const int a1 = min(lo, n1), e1 = min(hi, n1);
  const int a2 = max(lo - n1, 0), e2 = max(hi - n1, 0);

  attn_tile(b, j1, a1, e1, wave, quad, l16, lane, sp, Qf, Kf, Vf, Ks, Vs, Opart, lpart);
  attn_tile(b, j2, a2, e2, wave, quad, l16, lane, sp, Qf, Kf, Vf, Ks, Vs, Opart, lpart);
}

// ---------------------------------------------------------------------------
// Combine S split partials: out = sum_s O_s / sum_s l_s
// ---------------------------------------------------------------------------
__global__ __launch_bounds__(256) void combine_kernel(
    const float* __restrict__ Opart, const float* __restrict__ lpart,
    float* __restrict__ out, int S)
{
  const int idx = blockIdx.x * 256 + threadIdx.x;
  const int row = idx >> 4;
  const int c   = (idx & 15) * 4;
  float l = 0.f;
  f32x4 s = (f32x4){0.f, 0.f, 0.f, 0.f};
  for (int p = 0; p < S; ++p) {
    l += lpart[(size_t)p * BB * TT + row];
    s += *(const f32x4*)&Opart[((size_t)p * BB * TT + row) * HH + c];
  }
  const float inv = 1.0f / l;
  *(f32x4*)&out[(size_t)row * HH + c] = s * inv;
}

// ---------------------------------------------------------------------------
extern "C" void kernel_launch(void* const* d_in, const int* in_sizes, int n_in,
                              void* d_out, int out_size, void* d_ws, size_t ws_size,
                              hipStream_t stream)
{
  const float* q  = (const float*)d_in[0];
  const float* k  = (const float*)d_in[1];
  const float* v  = (const float*)d_in[2];
  const float* Wq = (const float*)d_in[3];
  const float* Wk = (const float*)d_in[4];
  const float* Wv = (const float*)d_in[5];
  float* out = (float*)d_out;

  const size_t n = (size_t)BB * TT * HH;   // 1,048,576 f16 per tensor
  const size_t need8 = (WF_ELEMS + 3 * n) * sizeof(f16)
                     + 8 * n * sizeof(float) + 8 * (size_t)BB * TT * sizeof(float);
  const int S = (ws_size >= need8) ? 8 : 4;

  f16* Wf = (f16*)d_ws;
  f16* Qf = Wf + WF_ELEMS;
  f16* Kf = Qf + n;
  f16* Vf = Kf + n;
  float* Opart = (float*)(Vf + n);
  float* lpart = Opart + (size_t)S * n;

  wrepack_kernel<<<dim3(384), 64, 0, stream>>>(Wq, Wk, Wv, Wf);
  proj_kernel<<<dim3(256, 3), 256, 0, stream>>>(q, k, v, Wf, Qf, Kf, Vf);
  attn_kernel<<<dim3(32, S, BB), 256, 0, stream>>>(Qf, Kf, Vf, Opart, lpart, S);
  combine_kernel<<<dim3(1024), 256, 0, stream>>>(Opart, lpart, out, S);
}

// Round 5
// 235.640 us; speedup vs baseline: 1.0731x; 1.0731x over previous
//
#include <hip/hip_runtime.h>
#include <hip/hip_bf16.h>

#define BB 4
#define TT 4096
#define CC 1024
#define HH 64

typedef _Float16 f16;
typedef __attribute__((ext_vector_type(8))) _Float16 f16x8;
typedef __attribute__((ext_vector_type(4))) _Float16 f16x4;
typedef __attribute__((ext_vector_type(4))) float f32x4;

#define MFMA32(a,b,c) __builtin_amdgcn_mfma_f32_16x16x32_f16((a),(b),(c),0,0,0)
#define MFMA16(a,b,c) __builtin_amdgcn_mfma_f32_16x16x16f16((a),(b),(c),0,0,0)

// frag-major sizes (f16 units)
#define WF_ELEMS (3 * 32 * 4 * 64 * 8)        // 196,608
#define CHUNK_F16 1024                        // per 16-row chunk: 2 halves x 64 lanes x 8
#define PB_F16 (256 * CHUNK_F16)              // per batch: 256 chunks

// Async global->LDS, 16B per lane. Side-effecting: compiler cannot sink it.
// LDS dest must be wave-uniform; lane i's 16B lands at dest + i*16.
static __device__ __forceinline__ void gl_lds16(const void* g, void* l) {
  __builtin_amdgcn_global_load_lds(
      (const __attribute__((address_space(1))) unsigned int*)g,
      (__attribute__((address_space(3))) unsigned int*)l, 16, 0, 0);
}

static __device__ __forceinline__ f16x8 pack2(f32x4 a, f32x4 b) {
  f16x8 r;
  r[0]=(f16)a[0]; r[1]=(f16)a[1]; r[2]=(f16)a[2]; r[3]=(f16)a[3];
  r[4]=(f16)b[0]; r[5]=(f16)b[1]; r[6]=(f16)b[2]; r[7]=(f16)b[3];
  return r;
}

// ---------------------------------------------------------------------------
// Repack W -> frag-major f16. Block bx = (p*32+kc)*4+nt, 64 threads.
// Softmax double-scale log2(e)/64 folded into Wq.
// ---------------------------------------------------------------------------
__global__ __launch_bounds__(64) void wrepack_kernel(
    const float* __restrict__ Wqg, const float* __restrict__ Wkg,
    const float* __restrict__ Wvg, f16* __restrict__ Wf)
{
  const int bx = blockIdx.x;
  const int nt = bx & 3;
  const int kc = (bx >> 2) & 31;
  const int p  = bx >> 7;
  const float* W = (p == 0) ? Wqg : (p == 1) ? Wkg : Wvg;
  const float sc = (p == 0) ? (1.4426950408889634f / 64.0f) : 1.0f;

  const int lane = threadIdx.x;
  const int l16 = lane & 15, quad = lane >> 4;
  const float* src = W + (size_t)(nt * 16 + l16) * CC + kc * 32 + quad * 8;
  f32x4 a = *(const f32x4*)src;
  f32x4 b = *(const f32x4*)(src + 4);
  f16x8 r;
  #pragma unroll
  for (int j = 0; j < 4; ++j) { r[j] = (f16)(a[j] * sc); r[j + 4] = (f16)(b[j] * sc); }
  *(f16x8*)(Wf + (size_t)bx * 512 + lane * 8) = r;
}

// ---------------------------------------------------------------------------
// Projection: X[16384,1024] fp32 x W^T -> frag-major f16.
// R0 structure (best measured: 78us) with ONE change: W fragments are no
// longer staged through LDS via global_load_lds. Rationale: every block
// re-staged 128KB of W (98MB chip-wide, ~1/3 of all staged bytes) through
// the same per-CU ingest pipe as X, and gl_lds BYPASSES L1 so the L2-hot W
// could never be served locally. All 5 prior variants pinned at ~5.8 B/cyc/CU
// total ingest -- removing the W bytes is the one untried lever. Now the 8
// B-frag loads per iter are plain per-lane loads: all 4 waves (and ~4
// blocks/CU) touch the SAME 8KB of W per iteration, so L1 serves most of
// them. X staging (dbuf gl_lds, XOR-swizzled chunks) is byte-identical to
// R0. LDS drops 48->32KB; launch_bounds(256,4) caps VGPR at 128 so the W
// loads can schedule early.
// ---------------------------------------------------------------------------
__global__ __launch_bounds__(256, 4) void proj_kernel(
    const float* __restrict__ qg, const float* __restrict__ kg, const float* __restrict__ vg,
    const f16* __restrict__ Wf,
    f16* __restrict__ Qf, f16* __restrict__ Kf, f16* __restrict__ Vf)
{
  __shared__ float Xs[2][64][64];     // 32 KB

  const float* X; f16* O; const int p = blockIdx.y;
  if (p == 0)      { X = qg; O = Qf; }
  else if (p == 1) { X = kg; O = Kf; }
  else             { X = vg; O = Vf; }

  const int tid  = threadIdx.x;
  const int w    = tid >> 6;
  const int lane = tid & 63;
  const int quad = lane >> 4;
  const int l16  = lane & 15;
  const int r0   = blockIdx.x * 64;

  // X staging: inst s (s=0..3 per wave) covers rows R = w*16+s*4+(lane>>4).
  // Stored phys chunk pc = lane&15 holds logical chunk lc = pc ^ ((R&7)<<1).
  const float* Xrow[4];
  #pragma unroll
  for (int s = 0; s < 4; ++s) {
    const int R  = w * 16 + s * 4 + (lane >> 4);
    const int lc = (lane & 15) ^ ((R & 7) << 1);
    Xrow[s] = X + (size_t)(r0 + R) * CC + lc * 4;
  }
  // B-frag source: frag-major W, 16B per lane; frag-block (it*2+kk)*4+nt.
  const f16* wbase = Wf + (size_t)p * 128 * 512 + lane * 8;

  f32x4 acc[4];
  #pragma unroll
  for (int nt = 0; nt < 4; ++nt) acc[nt] = (f32x4){0.f, 0.f, 0.f, 0.f};

  // initial stage: it=0 -> buf 0
  #pragma unroll
  for (int s = 0; s < 4; ++s)
    gl_lds16(Xrow[s], &Xs[0][w * 16 + s * 4][0]);

  const int sw = (l16 & 7) << 1;   // frag-read swizzle (R&7 == l16&7 for row w*16+l16)

  for (int it = 0; it < 16; ++it) {
    const int buf = it & 1;
    __syncthreads();   // vmcnt(0) drains staging of buf; joins prev compute
    if (it < 15) {
      #pragma unroll
      for (int s = 0; s < 4; ++s)
        gl_lds16(Xrow[s] + (it + 1) * 64, &Xs[buf ^ 1][w * 16 + s * 4][0]);
    }
    #pragma unroll
    for (int kk = 0; kk < 2; ++kk) {
      const int c0 = kk * 8 + quad * 2;
      f32x4 a0 = *(const f32x4*)&Xs[buf][w * 16 + l16][(c0 ^ sw) * 4];
      f32x4 a1 = *(const f32x4*)&Xs[buf][w * 16 + l16][((c0 + 1) ^ sw) * 4];
      f16x8 af = pack2(a0, a1);
      #pragma unroll
      for (int nt = 0; nt < 4; ++nt) {
        f16x8 bf = *(const f16x8*)(wbase + (size_t)((it * 2 + kk) * 4 + nt) * 512);
        acc[nt] = MFMA32(af, bf, acc[nt]);
      }
    }
  }

  // epilogue: C-layout acc -> frag-major via wave-private LDS region.
  // Xs[0] rows w*16..w*16+15 (4 KB/wave) are free: last read was it=14,
  // protected by it=15's barrier. No extra barrier needed (wave-private).
  f16 (*Ls)[66] = (f16(*)[66])&Xs[0][w * 16][0];
  #pragma unroll
  for (int nt = 0; nt < 4; ++nt)
    #pragma unroll
    for (int r = 0; r < 4; ++r)
      Ls[quad * 4 + r][nt * 16 + l16] = (f16)acc[nt][r];
  const size_t chunk = (size_t)blockIdx.x * 4 + w;
  if (p < 2) {
    // Q/K frag: [chunk][half][lane][8] = tile[row=l16][hd=32h+8q+j]
    #pragma unroll
    for (int h = 0; h < 2; ++h) {
      f16x8 t = *(const f16x8*)&Ls[l16][h * 32 + quad * 8];
      *(f16x8*)(O + (chunk * 2 + h) * 512 + lane * 8) = t;
    }
  } else {
    // V frag: [chunk][np][lane][8] = tile[key=4q+(j&3)][hd=(2np+(j>>2))*16+l16]
    #pragma unroll
    for (int np = 0; np < 2; ++np) {
      f16x8 t;
      #pragma unroll
      for (int j = 0; j < 8; ++j)
        t[j] = Ls[quad * 4 + (j & 3)][(2 * np + (j >> 2)) * 16 + l16];
      *(f16x8*)(O + (chunk * 2 + np) * 512 + lane * 8) = t;
    }
  }
}

// ---------------------------------------------------------------------------
// Flash attention, mask s <= t+1. Block-wide double-buffered async staging of
// K and V steps (each step = contiguous 8 KB in frag-major layout). Frag reads
// are lane-linear ds_read_b128 (conflict-free). Uniform trip counts.
// S^T via MFMA(A=K,B=Q); P C-layout == MFMA16 A-layout. Scale folded into Wq.
// ---------------------------------------------------------------------------
__device__ __forceinline__ void attn_tile(
    int b, int j, int a, int e, int wave, int quad, int l16, int lane, int sp,
    const f16* __restrict__ Qf, const f16* __restrict__ Kf, const f16* __restrict__ Vf,
    f16 (*Ks)[8][64][8], f16 (*Vs)[8][64][8],
    float* __restrict__ Opart, float* __restrict__ lpart)
{
  const int m0 = j * 64 + wave * 16;

  const f16* Kfb = Kf + (size_t)b * PB_F16;
  const f16* Vfb = Vf + (size_t)b * PB_F16;
  const f16* Qfb = Qf + (size_t)b * PB_F16;

  f16x8 qa0 = *(const f16x8*)(Qfb + ((size_t)(m0 >> 4) * 2 + 0) * 512 + lane * 8);
  f16x8 qa1 = *(const f16x8*)(Qfb + ((size_t)(m0 >> 4) * 2 + 1) * 512 + lane * 8);

  f32x4 o[4];
  float lsum = 0.f;
  #pragma unroll
  for (int nt = 0; nt < 4; ++nt) o[nt] = (f32x4){0.f, 0.f, 0.f, 0.f};

  // protect staging buffers from the previous tile's laggard readers
  __syncthreads();

  if (a < e) {
    #pragma unroll
    for (int jj = 0; jj < 2; ++jj) {
      const int idx = 2 * wave + jj;
      gl_lds16(Kfb + (size_t)a * 4096 + idx * 512 + lane * 8, &Ks[0][idx][0][0]);
      gl_lds16(Vfb + (size_t)a * 4096 + idx * 512 + lane * 8, &Vs[0][idx][0][0]);
    }
  }

  for (int st = a; st < e; ++st) {
    const int buf = (st - a) & 1;
    __syncthreads();   // drains staging of buf
    if (st + 1 < e) {
      #pragma unroll
      for (int jj = 0; jj < 2; ++jj) {
        const int idx = 2 * wave + jj;
        gl_lds16(Kfb + (size_t)(st + 1) * 4096 + idx * 512 + lane * 8, &Ks[buf ^ 1][idx][0][0]);
        gl_lds16(Vfb + (size_t)(st + 1) * 4096 + idx * 512 + lane * 8, &Vs[buf ^ 1][idx][0][0]);
      }
    }
    const int s0 = st * 64;

    // S^T = K Q^T (scale pre-folded into Q)
    f32x4 sc[4];
    #pragma unroll
    for (int ct = 0; ct < 4; ++ct) {
      f16x8 k0 = *(const f16x8*)&Ks[buf][ct * 2][lane][0];
      f16x8 k1 = *(const f16x8*)&Ks[buf][ct * 2 + 1][lane][0];
      f32x4 z = (f32x4){0.f, 0.f, 0.f, 0.f};
      z = MFMA32(k0, qa0, z);
      sc[ct] = MFMA32(k1, qa1, z);
    }

    // mask + exp2; lane: query=m0+l16, key=s0+ct*16+quad*4+r
    const bool domask = (s0 + 63) > (m0 + 1);
    f16x4 pa[4];
    #pragma unroll
    for (int ct = 0; ct < 4; ++ct) {
      #pragma unroll
      for (int r = 0; r < 4; ++r) {
        float x = sc[ct][r];
        if (domask) {
          const int key = s0 + ct * 16 + quad * 4 + r;
          if (key > m0 + l16 + 1) x = -__builtin_inff();
        }
        const float pv = __builtin_amdgcn_exp2f(x);
        lsum += pv;
        pa[ct][r] = (f16)pv;
      }
    }

    // PV: A=P (MFMA16 A-layout), B=V frag halves
    #pragma unroll
    for (int ct = 0; ct < 4; ++ct) {
      #pragma unroll
      for (int np = 0; np < 2; ++np) {
        f16x8 vv = *(const f16x8*)&Vs[buf][ct * 2 + np][lane][0];
        f16x4 blo = __builtin_shufflevector(vv, vv, 0, 1, 2, 3);
        f16x4 bhi = __builtin_shufflevector(vv, vv, 4, 5, 6, 7);
        o[2 * np]     = MFMA16(pa[ct], blo, o[2 * np]);
        o[2 * np + 1] = MFMA16(pa[ct], bhi, o[2 * np + 1]);
      }
    }
  }

  lsum += __shfl_xor(lsum, 16, 64);
  lsum += __shfl_xor(lsum, 32, 64);
  const size_t rbase = (size_t)(sp * BB + b) * TT;
  if (quad == 0) lpart[rbase + m0 + l16] = lsum;
  #pragma unroll
  for (int nt = 0; nt < 4; ++nt)
    #pragma unroll
    for (int r = 0; r < 4; ++r)
      Opart[(rbase + m0 + quad * 4 + r) * HH + nt * 16 + l16] = o[nt][r];
}

__global__ __launch_bounds__(256) void attn_kernel(
    const f16* __restrict__ Qf, const f16* __restrict__ Kf, const f16* __restrict__ Vf,
    float* __restrict__ Opart, float* __restrict__ lpart, int S)
{
  __shared__ f16 Ks[2][8][64][8];   // 16 KB
  __shared__ f16 Vs[2][8][64][8];   // 16 KB

  const int pr = blockIdx.x;
  const int sp = blockIdx.y;
  const int b  = blockIdx.z;
  const int tid  = threadIdx.x;
  const int wave = tid >> 6;
  const int lane = tid & 63;
  const int quad = lane >> 4;
  const int l16  = lane & 15;

  const int j1 = pr, j2 = 63 - pr;
  const int n1 = min(j1 + 2, 64), n2 = min(j2 + 2, 64);
  const int tot = n1 + n2;
  const int lo = tot * sp / S, hi = tot * (sp + 1) / S;
  const int a1 = min(lo, n1), e1 = min(hi, n1);
  const int a2 = max(lo - n1, 0), e2 = max(hi - n1, 0);

  attn_tile(b, j1, a1, e1, wave, quad, l16, lane, sp, Qf, Kf, Vf, Ks, Vs, Opart, lpart);
  attn_tile(b, j2, a2, e2, wave, quad, l16, lane, sp, Qf, Kf, Vf, Ks, Vs, Opart, lpart);
}

// ---------------------------------------------------------------------------
// Combine S split partials: out = sum_s O_s / sum_s l_s
// ---------------------------------------------------------------------------
__global__ __launch_bounds__(256) void combine_kernel(
    const float* __restrict__ Opart, const float* __restrict__ lpart,
    float* __restrict__ out, int S)
{
  const int idx = blockIdx.x * 256 + threadIdx.x;
  const int row = idx >> 4;
  const int c   = (idx & 15) * 4;
  float l = 0.f;
  f32x4 s = (f32x4){0.f, 0.f, 0.f, 0.f};
  for (int p = 0; p < S; ++p) {
    l += lpart[(size_t)p * BB * TT + row];
    s += *(const f32x4*)&Opart[((size_t)p * BB * TT + row) * HH + c];
  }
  const float inv = 1.0f / l;
  *(f32x4*)&out[(size_t)row * HH + c] = s * inv;
}

// ---------------------------------------------------------------------------
extern "C" void kernel_launch(void* const* d_in, const int* in_sizes, int n_in,
                              void* d_out, int out_size, void* d_ws, size_t ws_size,
                              hipStream_t stream)
{
  const float* q  = (const float*)d_in[0];
  const float* k  = (const float*)d_in[1];
  const float* v  = (const float*)d_in[2];
  const float* Wq = (const float*)d_in[3];
  const float* Wk = (const float*)d_in[4];
  const float* Wv = (const float*)d_in[5];
  float* out = (float*)d_out;

  const size_t n = (size_t)BB * TT * HH;   // 1,048,576 f16 per tensor
  const size_t need8 = (WF_ELEMS + 3 * n) * sizeof(f16)
                     + 8 * n * sizeof(float) + 8 * (size_t)BB * TT * sizeof(float);
  const int S = (ws_size >= need8) ? 8 : 4;

  f16* Wf = (f16*)d_ws;
  f16* Qf = Wf + WF_ELEMS;
  f16* Kf = Qf + n;
  f16* Vf = Kf + n;
  float* Opart = (float*)(Vf + n);
  float* lpart = Opart + (size_t)S * n;

  wrepack_kernel<<<dim3(384), 64, 0, stream>>>(Wq, Wk, Wv, Wf);
  proj_kernel<<<dim3(256, 3), 256, 0, stream>>>(q, k, v, Wf, Qf, Kf, Vf);
  attn_kernel<<<dim3(32, S, BB), 256, 0, stream>>>(Qf, Kf, Vf, Opart, lpart, S);
  combine_kernel<<<dim3(1024), 256, 0, stream>>>(Opart, lpart, out, S);
}

// Round 6
// 234.598 us; speedup vs baseline: 1.0779x; 1.0044x over previous
//
#include <hip/hip_runtime.h>
#include <hip/hip_bf16.h>

#define BB 4
#define TT 4096
#define CC 1024
#define HH 64

typedef _Float16 f16;
typedef __attribute__((ext_vector_type(8))) _Float16 f16x8;
typedef __attribute__((ext_vector_type(4))) _Float16 f16x4;
typedef __attribute__((ext_vector_type(4))) float f32x4;

#define MFMA32(a,b,c) __builtin_amdgcn_mfma_f32_16x16x32_f16((a),(b),(c),0,0,0)
#define MFMA16(a,b,c) __builtin_amdgcn_mfma_f32_16x16x16f16((a),(b),(c),0,0,0)

// frag-major sizes (f16 units)
#define WF_ELEMS (3 * 32 * 4 * 64 * 8)        // 196,608
#define CHUNK_F16 1024                        // per 16-row chunk: 2 halves x 64 lanes x 8
#define PB_F16 (256 * CHUNK_F16)              // per batch: 256 chunks

// Async global->LDS, 16B per lane. Side-effecting: compiler cannot sink it.
// LDS dest must be wave-uniform; lane i's 16B lands at dest + i*16.
static __device__ __forceinline__ void gl_lds16(const void* g, void* l) {
  __builtin_amdgcn_global_load_lds(
      (const __attribute__((address_space(1))) unsigned int*)g,
      (__attribute__((address_space(3))) unsigned int*)l, 16, 0, 0);
}

static __device__ __forceinline__ f16x8 pack2(f32x4 a, f32x4 b) {
  f16x8 r;
  r[0]=(f16)a[0]; r[1]=(f16)a[1]; r[2]=(f16)a[2]; r[3]=(f16)a[3];
  r[4]=(f16)b[0]; r[5]=(f16)b[1]; r[6]=(f16)b[2]; r[7]=(f16)b[3];
  return r;
}

// ---------------------------------------------------------------------------
// Repack W -> frag-major f16. Block bx = (p*32+kc)*4+nt, 64 threads.
// Softmax double-scale log2(e)/64 folded into Wq.
// ---------------------------------------------------------------------------
__global__ __launch_bounds__(64) void wrepack_kernel(
    const float* __restrict__ Wqg, const float* __restrict__ Wkg,
    const float* __restrict__ Wvg, f16* __restrict__ Wf)
{
  const int bx = blockIdx.x;
  const int nt = bx & 3;
  const int kc = (bx >> 2) & 31;
  const int p  = bx >> 7;
  const float* W = (p == 0) ? Wqg : (p == 1) ? Wkg : Wvg;
  const float sc = (p == 0) ? (1.4426950408889634f / 64.0f) : 1.0f;

  const int lane = threadIdx.x;
  const int l16 = lane & 15, quad = lane >> 4;
  const float* src = W + (size_t)(nt * 16 + l16) * CC + kc * 32 + quad * 8;
  f32x4 a = *(const f32x4*)src;
  f32x4 b = *(const f32x4*)(src + 4);
  f16x8 r;
  #pragma unroll
  for (int j = 0; j < 4; ++j) { r[j] = (f16)(a[j] * sc); r[j + 4] = (f16)(b[j] * sc); }
  *(f16x8*)(Wf + (size_t)bx * 512 + lane * 8) = r;
}

// ---------------------------------------------------------------------------
// Projection: X[16384,1024] fp32 x W^T -> frag-major f16.
// Reg-staged, BARRIER-FREE pipeline. Key observations after R0-R5 (all
// 78-93us, ~1.3 TB/s):
//  (1) gl_lds variants never had >2 stages in flight (the __syncthreads or
//      counted-vmcnt structures drained/burst-synced); plain-load variants
//      (R1/R4) were collapsed by the compiler (VGPR 36-56 = ~1 load in
//      flight). Nothing ever sustained deep per-wave MLP on the X stream.
//  (2) X staging here is entirely WAVE-PRIVATE (wave w stages and consumes
//      only rows w*16..w*16+15) -> no barriers are needed at all.
// Structure per wave, per 64-col step: load next 4KB batch into registers
// (4x global_load_dwordx4/lane), sched_barrier(0) fence (pins issue BEFORE
// the waits below - rule #18), ds_write current batch (compiler inserts the
// minimal vmcnt staircase for the data dep - CANNOT be eliminated), fence,
// then ds_read + MFMA. Every wave is an independent continuously-pipelined
// stream: 12 waves/CU x 4KB in flight, no vmcnt(0) drains anywhere.
// LDS image identical to R5: phys 16B-chunk pc of row R holds logical
// pc ^ ((R&7)<<1) (swizzle now applied on the ds_write address; global
// loads are straight-contiguous). Compute/epilogue byte-identical to R5.
// ---------------------------------------------------------------------------
__global__ __launch_bounds__(256, 3) void proj_kernel(
    const float* __restrict__ qg, const float* __restrict__ kg, const float* __restrict__ vg,
    const f16* __restrict__ Wf,
    f16* __restrict__ Qf, f16* __restrict__ Kf, f16* __restrict__ Vf)
{
  __shared__ float Xs[2][64][64];     // 32 KB, wave-private 16-row stripes

  const float* X; f16* O; const int p = blockIdx.y;
  if (p == 0)      { X = qg; O = Qf; }
  else if (p == 1) { X = kg; O = Kf; }
  else             { X = vg; O = Vf; }

  const int tid  = threadIdx.x;
  const int w    = tid >> 6;
  const int lane = tid & 63;
  const int quad = lane >> 4;
  const int l16  = lane & 15;
  const int r0   = blockIdx.x * 64;

  // Staging geometry: inst s covers rows R = w*16+s*4+(lane>>4); lane reads
  // logical 16B-chunk (lane&15) of that row (contiguous 256B per 16 lanes)
  // and ds_writes it to phys chunk (lane&15) ^ ((R&7)<<1).
  const float* Xld[4];
  int wr[4], ws[4];
  #pragma unroll
  for (int s = 0; s < 4; ++s) {
    const int R = w * 16 + s * 4 + (lane >> 4);
    Xld[s] = X + (size_t)(r0 + R) * CC + (lane & 15) * 4;
    wr[s] = R;
    ws[s] = ((lane & 15) ^ ((R & 7) << 1)) * 4;
  }
  // B-frag source: frag-major W, 16B per lane; frag-block (it*2+kk)*4+nt.
  // 128KB/tensor shared by all blocks -> L1/L2-hot plain loads.
  const f16* wbase = Wf + (size_t)p * 128 * 512 + lane * 8;

  f32x4 acc[4];
  #pragma unroll
  for (int nt = 0; nt < 4; ++nt) acc[nt] = (f32x4){0.f, 0.f, 0.f, 0.f};

  const int sw = (l16 & 7) << 1;   // frag-read swizzle (row w*16+l16 -> R&7 == l16&7)

  f32x4 La[4], Lb[4];
  #pragma unroll
  for (int s = 0; s < 4; ++s) La[s] = *(const f32x4*)(Xld[s]);   // batch 0

#define PROJ_PHASE(IT, BUF, CUR, NXT)                                         \
  {                                                                           \
    const int itn = ((IT) < 15) ? (IT) + 1 : 15;                              \
    _Pragma("unroll")                                                         \
    for (int s = 0; s < 4; ++s)                                               \
      NXT[s] = *(const f32x4*)(Xld[s] + itn * 64);                            \
    __builtin_amdgcn_sched_barrier(0);                                        \
    _Pragma("unroll")                                                         \
    for (int s = 0; s < 4; ++s)                                               \
      *(f32x4*)&Xs[BUF][wr[s]][ws[s]] = CUR[s];                               \
    __builtin_amdgcn_sched_barrier(0);                                        \
    _Pragma("unroll")                                                         \
    for (int kk = 0; kk < 2; ++kk) {                                          \
      const int c0 = kk * 8 + quad * 2;                                       \
      f32x4 a0 = *(const f32x4*)&Xs[BUF][w * 16 + l16][(c0 ^ sw) * 4];        \
      f32x4 a1 = *(const f32x4*)&Xs[BUF][w * 16 + l16][((c0 + 1) ^ sw) * 4];  \
      f16x8 af = pack2(a0, a1);                                               \
      _Pragma("unroll")                                                       \
      for (int nt = 0; nt < 4; ++nt) {                                        \
        f16x8 bf = *(const f16x8*)(wbase + (size_t)(((IT) * 2 + kk) * 4 + nt) * 512); \
        acc[nt] = MFMA32(af, bf, acc[nt]);                                    \
      }                                                                       \
    }                                                                         \
  }

  #pragma unroll
  for (int ih = 0; ih < 8; ++ih) {
    PROJ_PHASE(2 * ih,     0, La, Lb)
    PROJ_PHASE(2 * ih + 1, 1, Lb, La)
  }
#undef PROJ_PHASE

  // epilogue: C-layout acc -> frag-major via wave-private LDS region
  // (Xs[0] rows w*16..w*16+15; same-wave lgkm ordering, no barrier needed).
  f16 (*Ls)[66] = (f16(*)[66])&Xs[0][w * 16][0];
  #pragma unroll
  for (int nt = 0; nt < 4; ++nt)
    #pragma unroll
    for (int r = 0; r < 4; ++r)
      Ls[quad * 4 + r][nt * 16 + l16] = (f16)acc[nt][r];
  const size_t chunk = (size_t)blockIdx.x * 4 + w;
  if (p < 2) {
    // Q/K frag: [chunk][half][lane][8] = tile[row=l16][hd=32h+8q+j]
    #pragma unroll
    for (int h = 0; h < 2; ++h) {
      f16x8 t = *(const f16x8*)&Ls[l16][h * 32 + quad * 8];
      *(f16x8*)(O + (chunk * 2 + h) * 512 + lane * 8) = t;
    }
  } else {
    // V frag: [chunk][np][lane][8] = tile[key=4q+(j&3)][hd=(2np+(j>>2))*16+l16]
    #pragma unroll
    for (int np = 0; np < 2; ++np) {
      f16x8 t;
      #pragma unroll
      for (int j = 0; j < 8; ++j)
        t[j] = Ls[quad * 4 + (j & 3)][(2 * np + (j >> 2)) * 16 + l16];
      *(f16x8*)(O + (chunk * 2 + np) * 512 + lane * 8) = t;
    }
  }
}

// ---------------------------------------------------------------------------
// Flash attention, mask s <= t+1. Block-wide double-buffered async staging of
// K and V steps (each step = contiguous 8 KB in frag-major layout). Frag reads
// are lane-linear ds_read_b128 (conflict-free). Uniform trip counts.
// S^T via MFMA(A=K,B=Q); P C-layout == MFMA16 A-layout. Scale folded into Wq.
// ---------------------------------------------------------------------------
__device__ __forceinline__ void attn_tile(
    int b, int j, int a, int e, int wave, int quad, int l16, int lane, int sp,
    const f16* __restrict__ Qf, const f16* __restrict__ Kf, const f16* __restrict__ Vf,
    f16 (*Ks)[8][64][8], f16 (*Vs)[8][64][8],
    float* __restrict__ Opart, float* __restrict__ lpart)
{
  const int m0 = j * 64 + wave * 16;

  const f16* Kfb = Kf + (size_t)b * PB_F16;
  const f16* Vfb = Vf + (size_t)b * PB_F16;
  const f16* Qfb = Qf + (size_t)b * PB_F16;

  f16x8 qa0 = *(const f16x8*)(Qfb + ((size_t)(m0 >> 4) * 2 + 0) * 512 + lane * 8);
  f16x8 qa1 = *(const f16x8*)(Qfb + ((size_t)(m0 >> 4) * 2 + 1) * 512 + lane * 8);

  f32x4 o[4];
  float lsum = 0.f;
  #pragma unroll
  for (int nt = 0; nt < 4; ++nt) o[nt] = (f32x4){0.f, 0.f, 0.f, 0.f};

  // protect staging buffers from the previous tile's laggard readers
  __syncthreads();

  if (a < e) {
    #pragma unroll
    for (int jj = 0; jj < 2; ++jj) {
      const int idx = 2 * wave + jj;
      gl_lds16(Kfb + (size_t)a * 4096 + idx * 512 + lane * 8, &Ks[0][idx][0][0]);
      gl_lds16(Vfb + (size_t)a * 4096 + idx * 512 + lane * 8, &Vs[0][idx][0][0]);
    }
  }

  for (int st = a; st < e; ++st) {
    const int buf = (st - a) & 1;
    __syncthreads();   // drains staging of buf
    if (st + 1 < e) {
      #pragma unroll
      for (int jj = 0; jj < 2; ++jj) {
        const int idx = 2 * wave + jj;
        gl_lds16(Kfb + (size_t)(st + 1) * 4096 + idx * 512 + lane * 8, &Ks[buf ^ 1][idx][0][0]);
        gl_lds16(Vfb + (size_t)(st + 1) * 4096 + idx * 512 + lane * 8, &Vs[buf ^ 1][idx][0][0]);
      }
    }
    const int s0 = st * 64;

    // S^T = K Q^T (scale pre-folded into Q)
    f32x4 sc[4];
    #pragma unroll
    for (int ct = 0; ct < 4; ++ct) {
      f16x8 k0 = *(const f16x8*)&Ks[buf][ct * 2][lane][0];
      f16x8 k1 = *(const f16x8*)&Ks[buf][ct * 2 + 1][lane][0];
      f32x4 z = (f32x4){0.f, 0.f, 0.f, 0.f};
      z = MFMA32(k0, qa0, z);
      sc[ct] = MFMA32(k1, qa1, z);
    }

    // mask + exp2; lane: query=m0+l16, key=s0+ct*16+quad*4+r
    const bool domask = (s0 + 63) > (m0 + 1);
    f16x4 pa[4];
    #pragma unroll
    for (int ct = 0; ct < 4; ++ct) {
      #pragma unroll
      for (int r = 0; r < 4; ++r) {
        float x = sc[ct][r];
        if (domask) {
          const int key = s0 + ct * 16 + quad * 4 + r;
          if (key > m0 + l16 + 1) x = -__builtin_inff();
        }
        const float pv = __builtin_amdgcn_exp2f(x);
        lsum += pv;
        pa[ct][r] = (f16)pv;
      }
    }

    // PV: A=P (MFMA16 A-layout), B=V frag halves
    #pragma unroll
    for (int ct = 0; ct < 4; ++ct) {
      #pragma unroll
      for (int np = 0; np < 2; ++np) {
        f16x8 vv = *(const f16x8*)&Vs[buf][ct * 2 + np][lane][0];
        f16x4 blo = __builtin_shufflevector(vv, vv, 0, 1, 2, 3);
        f16x4 bhi = __builtin_shufflevector(vv, vv, 4, 5, 6, 7);
        o[2 * np]     = MFMA16(pa[ct], blo, o[2 * np]);
        o[2 * np + 1] = MFMA16(pa[ct], bhi, o[2 * np + 1]);
      }
    }
  }

  lsum += __shfl_xor(lsum, 16, 64);
  lsum += __shfl_xor(lsum, 32, 64);
  const size_t rbase = (size_t)(sp * BB + b) * TT;
  if (quad == 0) lpart[rbase + m0 + l16] = lsum;
  #pragma unroll
  for (int nt = 0; nt < 4; ++nt)
    #pragma unroll
    for (int r = 0; r < 4; ++r)
      Opart[(rbase + m0 + quad * 4 + r) * HH + nt * 16 + l16] = o[nt][r];
}

__global__ __launch_bounds__(256) void attn_kernel(
    const f16* __restrict__ Qf, const f16* __restrict__ Kf, const f16* __restrict__ Vf,
    float* __restrict__ Opart, float* __restrict__ lpart, int S)
{
  __shared__ f16 Ks[2][8][64][8];   // 16 KB
  __shared__ f16 Vs[2][8][64][8];   // 16 KB

  const int pr = blockIdx.x;
  const int sp = blockIdx.y;
  const int b  = blockIdx.z;
  const int tid  = threadIdx.x;
  const int wave = tid >> 6;
  const int lane = tid & 63;
  const int quad = lane >> 4;
  const int l16  = lane & 15;

  const int j1 = pr, j2 = 63 - pr;
  const int n1 = min(j1 + 2, 64), n2 = min(j2 + 2, 64);
  const int tot = n1 + n2;
  const int lo = tot * sp / S, hi = tot * (sp + 1) / S;
  const int a1 = min(lo, n1), e1 = min(hi, n1);
  const int a2 = max(lo - n1, 0), e2 = max(hi - n1, 0);

  attn_tile(b, j1, a1, e1, wave, quad, l16, lane, sp, Qf, Kf, Vf, Ks, Vs, Opart, lpart);
  attn_tile(b, j2, a2, e2, wave, quad, l16, lane, sp, Qf, Kf, Vf, Ks, Vs, Opart, lpart);
}

// ---------------------------------------------------------------------------
// Combine S split partials: out = sum_s O_s / sum_s l_s
// ---------------------------------------------------------------------------
__global__ __launch_bounds__(256) void combine_kernel(
    const float* __restrict__ Opart, const float* __restrict__ lpart,
    float* __restrict__ out, int S)
{
  const int idx = blockIdx.x * 256 + threadIdx.x;
  const int row = idx >> 4;
  const int c   = (idx & 15) * 4;
  float l = 0.f;
  f32x4 s = (f32x4){0.f, 0.f, 0.f, 0.f};
  for (int p = 0; p < S; ++p) {
    l += lpart[(size_t)p * BB * TT + row];
    s += *(const f32x4*)&Opart[((size_t)p * BB * TT + row) * HH + c];
  }
  const float inv = 1.0f / l;
  *(f32x4*)&out[(size_t)row * HH + c] = s * inv;
}

// ---------------------------------------------------------------------------
extern "C" void kernel_launch(void* const* d_in, const int* in_sizes, int n_in,
                              void* d_out, int out_size, void* d_ws, size_t ws_size,
                              hipStream_t stream)
{
  const float* q  = (const float*)d_in[0];
  const float* k  = (const float*)d_in[1];
  const float* v  = (const float*)d_in[2];
  const float* Wq = (const float*)d_in[3];
  const float* Wk = (const float*)d_in[4];
  const float* Wv = (const float*)d_in[5];
  float* out = (float*)d_out;

  const size_t n = (size_t)BB * TT * HH;   // 1,048,576 f16 per tensor
  const size_t need8 = (WF_ELEMS + 3 * n) * sizeof(f16)
                     + 8 * n * sizeof(float) + 8 * (size_t)BB * TT * sizeof(float);
  const int S = (ws_size >= need8) ? 8 : 4;

  f16* Wf = (f16*)d_ws;
  f16* Qf = Wf + WF_ELEMS;
  f16* Kf = Qf + n;
  f16* Vf = Kf + n;
  float* Opart = (float*)(Vf + n);
  float* lpart = Opart + (size_t)S * n;

  wrepack_kernel<<<dim3(384), 64, 0, stream>>>(Wq, Wk, Wv, Wf);
  proj_kernel<<<dim3(256, 3), 256, 0, stream>>>(q, k, v, Wf, Qf, Kf, Vf);
  attn_kernel<<<dim3(32, S, BB), 256, 0, stream>>>(Qf, Kf, Vf, Opart, lpart, S);
  combine_kernel<<<dim3(1024), 256, 0, stream>>>(Opart, lpart, out, S);
}